// Round 12
// baseline (108.481 us; speedup 1.0000x reference)
//
#include <hip/hip_runtime.h>
#include <hip/hip_bf16.h>

#define DI __device__ __forceinline__

typedef float f32x4 __attribute__((ext_vector_type(4)));
typedef float f32x16 __attribute__((ext_vector_type(16)));
typedef short s16x8 __attribute__((ext_vector_type(8)));
typedef unsigned short u16x4 __attribute__((ext_vector_type(4)));
typedef unsigned long long u64;

// Problem constants: N=2048, B=2, C=1024, H=16, HD=64, M=B*N=4096.

DI unsigned short f2bf(float x) {            // f32 -> bf16 RNE (epilogue use)
  union { float f; unsigned u; } v; v.f = x;
  unsigned r = 0x7fffu + ((v.u >> 16) & 1u);
  return (unsigned short)((v.u + r) >> 16);
}

DI unsigned cvtpk(float lo, float hi) {      // packed f32x2 -> bf16x2 (RNE)
  unsigned u;
  asm("v_cvt_pk_bf16_f32 %0, %1, %2" : "=v"(u) : "v"(lo), "v"(hi));
  return u;
}

DI float max3f(float a, float b, float c) {
  float d;
  asm("v_max3_f32 %0, %1, %2, %3" : "=v"(d) : "v"(a), "v"(b), "v"(c));
  return d;
}

DI f32x16 zero16() {
  f32x16 z;
#pragma unroll
  for (int i = 0; i < 16; ++i) z[i] = 0.f;
  return z;
}

DI float max16_3(const f32x16& a) {          // max3 tree: 8 instrs
  float m0 = max3f(a[0], a[1], a[2]);
  float m1 = max3f(a[3], a[4], a[5]);
  float m2 = max3f(a[6], a[7], a[8]);
  float m3 = max3f(a[9], a[10], a[11]);
  float m4 = max3f(a[12], a[13], a[14]);
  float n0 = max3f(m0, m1, m2);
  float n1 = max3f(m3, m4, a[15]);
  return fmaxf(n0, n1);
}

DI float sum16(const f32x16& a) {            // 4-level tree
  float s0 = a[0] + a[1],  s1 = a[2] + a[3];
  float s2 = a[4] + a[5],  s3 = a[6] + a[7];
  float s4 = a[8] + a[9],  s5 = a[10] + a[11];
  float s6 = a[12] + a[13], s7 = a[14] + a[15];
  s0 += s1; s2 += s3; s4 += s5; s6 += s7;
  return (s0 + s2) + (s4 + s6);
}

DI void gll16(const void* g, void* l) {      // async global->LDS, 16B/lane
  __builtin_amdgcn_global_load_lds(
      (const __attribute__((address_space(1))) void*)g,
      (__attribute__((address_space(3))) void*)l, 16, 0, 0);
}

DI f32x16 mfma32(s16x8 a, s16x8 b, f32x16 c) {
  return __builtin_amdgcn_mfma_f32_32x32x16_bf16(a, b, c, 0, 0, 0);
}

DI f32x4 mfma16(s16x8 a, s16x8 b, f32x4 c) {
  return __builtin_amdgcn_mfma_f32_16x16x32_bf16(a, b, c, 0, 0, 0);
}

// ---------------- prep: weight transpose/convert + query cvt ----------------
// bid<2048: qbf[row=b*2048+n][c]=bf16(query[n][b][c]); else wconv (1088 tiles).
__global__ __launch_bounds__(256) void prep_kernel(
    const float* __restrict__ q, unsigned short* __restrict__ qbf,
    const float* __restrict__ Wq, const float* __restrict__ Wk,
    const float* __restrict__ Wv, const float* __restrict__ Wp,
    unsigned short* __restrict__ WqT, unsigned short* __restrict__ WkT,
    unsigned short* __restrict__ WvT, unsigned short* __restrict__ WpT)
{
  int bid = blockIdx.x;
  if (bid < 2048) {
    int gid = bid * 256 + threadIdx.x;    // 524288
    int row = gid >> 7;
    int c8 = (gid & 127) << 3;
    int b = row >> 11, n = row & 2047;
    size_t soff = ((size_t)n * 2 + b) * 1024 + c8;
    f32x4 v0 = *(const f32x4*)(q + soff);
    f32x4 v1 = *(const f32x4*)(q + soff + 4);
    union { unsigned u[4]; s16x8 v; } x;
    x.u[0] = cvtpk(v0.x, v0.y); x.u[1] = cvtpk(v0.z, v0.w);
    x.u[2] = cvtpk(v1.x, v1.y); x.u[3] = cvtpk(v1.z, v1.w);
    *(s16x8*)(qbf + (size_t)row * 1024 + c8) = x.v;
    return;
  }
  int wb = bid - 2048;
  const float* W; unsigned short* WT; int Ncols; int base;
  if (wb < 512)       { W = Wq; WT = WqT; Ncols = 1024; base = wb; }
  else if (wb < 1024) { W = Wp; WT = WpT; Ncols = 1024; base = wb - 512; }
  else if (wb < 1056) { W = Wk; WT = WkT; Ncols = 64;   base = wb - 1024; }
  else                { W = Wv; WT = WvT; Ncols = 64;   base = wb - 1056; }
  int nb = base >> 5, kb = base & 31;              // 64-n x 32-k tile
  int n = nb * 64 + (threadIdx.x & 63);
  int k = kb * 32 + (threadIdx.x >> 6) * 8;
  float f[8];
#pragma unroll
  for (int i = 0; i < 8; ++i) f[i] = W[(size_t)(k + i) * Ncols + n];
  union { unsigned u[4]; s16x8 v; } x;
#pragma unroll
  for (int i = 0; i < 4; ++i) x.u[i] = cvtpk(f[2 * i], f[2 * i + 1]);
  *(s16x8*)(WT + (size_t)n * 1024 + k) = x.v;
}

// ---------------- GEMM16 body (bf16 A via gll, prefetch dbuf): BM=128,BN=64 -
// MODE 0: qproj (out bf16 * scale).  MODE 2: out-proj (f32, (N,B,C) remap).
// As: 2 bufs x 8192 shorts; Bs: 2 bufs x 4096 shorts.
template<int MODE>
DI void gemm16_body(const unsigned short* __restrict__ A,
                    const unsigned short* __restrict__ Bt,
                    const float* __restrict__ bias, void* __restrict__ Cpv,
                    float scale, int bx, int by,
                    unsigned short* As, unsigned short* Bs)
{
  const int tid = threadIdx.x;
  const int lane = tid & 63, wave = tid >> 6;
  const int l16 = lane & 15, kq = lane >> 4;
  const int wr = wave >> 1, wc = wave & 1;   // WROWS=64, WCOLS=32; MI=4, NJ=2
  const int row0 = bx * 128;
  const int col0 = by * 64;

  f32x4 acc[4][2];
#pragma unroll
  for (int mi = 0; mi < 4; ++mi)
#pragma unroll
    for (int nj = 0; nj < 2; ++nj) acc[mi][nj] = f32x4{0.f, 0.f, 0.f, 0.f};

  auto STAGE = [&](int bf, int kt) {
    const int k0 = kt * 64;
    char* Ad = (char*)As + bf * 16384;
    char* Bd = (char*)Bs + bf * 8192;
#pragma unroll
    for (int i = 0; i < 4; ++i) {
      int o = i * 4096 + tid * 16;
      int r = o >> 7, c = (o & 127) >> 1;
      gll16(A + (size_t)(row0 + r) * 1024 + k0 + c, Ad + i * 4096 + wave * 1024);
    }
#pragma unroll
    for (int i = 0; i < 2; ++i) {
      int o = i * 4096 + tid * 16;
      int r = o >> 7, c = (o & 127) >> 1;
      gll16(Bt + (size_t)(col0 + r) * 1024 + k0 + c, Bd + i * 4096 + wave * 1024);
    }
  };

  STAGE(0, 0);
  __syncthreads();                 // implicit vmcnt(0) drain -> buf0 ready
  int cur = 0;
  for (int kt = 0; kt < 16; ++kt) {
    if (kt + 1 < 16) STAGE(cur ^ 1, kt + 1);   // prefetch next (hidden)
#pragma unroll
    for (int ks = 0; ks < 2; ++ks) {
      s16x8 af[4]; s16x8 bf2[2];
#pragma unroll
      for (int mi = 0; mi < 4; ++mi)
        af[mi] = *(const s16x8*)(As + cur * 8192 + (wr * 64 + mi * 16 + l16) * 64 + ks * 32 + kq * 8);
#pragma unroll
      for (int nj = 0; nj < 2; ++nj)
        bf2[nj] = *(const s16x8*)(Bs + cur * 4096 + (wc * 32 + nj * 16 + l16) * 64 + ks * 32 + kq * 8);
#pragma unroll
      for (int mi = 0; mi < 4; ++mi)
#pragma unroll
        for (int nj = 0; nj < 2; ++nj)
          acc[mi][nj] = mfma16(af[mi], bf2[nj], acc[mi][nj]);
    }
    __syncthreads();               // drains prefetch vmcnt + guards buf reuse
    cur ^= 1;
  }

  // epilogue; 16x16 C/D: col=lane&15, row=(lane>>4)*4 + r  [m89-verified]
#pragma unroll
  for (int mi = 0; mi < 4; ++mi)
#pragma unroll
  for (int nj = 0; nj < 2; ++nj) {
    int col = col0 + wc * 32 + nj * 16 + l16;
    int rowb = row0 + wr * 64 + mi * 16 + kq * 4;
    float bv = bias[col];
#pragma unroll
    for (int r = 0; r < 4; ++r) {
      int row = rowb + r;
      float val = acc[mi][nj][r] + bv;
      if constexpr (MODE == 0) {
        ((unsigned short*)Cpv)[(size_t)row * 1024 + col] = f2bf(val * scale);
      } else {
        ((float*)Cpv)[(size_t)(row & 2047) * 2048 + (size_t)(row >> 11) * 1024 + col] = val;
      }
    }
  }
}

// ---------------- kv-proj body: A = key/value f32 (reg-staged), FULL K ------
// Writes kproj / vprojT directly (+bias). As/Bs: 2 bufs x 4096 shorts each.
DI void gemmkv_body(const float* __restrict__ Akey, const float* __restrict__ Aval,
                    const unsigned short* __restrict__ Wk,
                    const unsigned short* __restrict__ Wv,
                    const float* __restrict__ bk, const float* __restrict__ bv,
                    unsigned short* __restrict__ kproj,
                    unsigned short* __restrict__ vprojT,
                    int bx, int sel,
                    unsigned short* As, unsigned short* Bs)
{
  const int tid = threadIdx.x;
  const int lane = tid & 63, wave = tid >> 6;
  const int l16 = lane & 15, kq = lane >> 4;
  const int wr = wave >> 1, wc = wave & 1;   // WROWS=32, WCOLS=32; MI=2, NJ=2
  const float* Af = sel ? Aval : Akey;
  const unsigned short* Bt = sel ? Wv : Wk;
  const int row0 = bx * 64;

  const int ar = tid >> 2, ac = (tid & 3) * 16;     // A: row 0..63, 16 f32/thread
  const int gm = row0 + ar;
  const size_t grow = sel ? (size_t)gm * 1024
                          : (size_t)((gm & 2047) * 2 + (gm >> 11)) * 1024;  // key remap

  auto LOADA = [&](int kt, f32x4* a4) {
#pragma unroll
    for (int i = 0; i < 4; ++i)
      a4[i] = *(const f32x4*)(Af + grow + kt * 64 + ac + i * 4);
  };
  auto WRITEA = [&](int bf, const f32x4* a4) {
    union { unsigned u[8]; s16x8 v[2]; } x;
#pragma unroll
    for (int i = 0; i < 4; ++i) {
      x.u[2 * i]     = cvtpk(a4[i].x, a4[i].y);
      x.u[2 * i + 1] = cvtpk(a4[i].z, a4[i].w);
    }
    *(s16x8*)(As + bf * 4096 + ar * 64 + ac)     = x.v[0];
    *(s16x8*)(As + bf * 4096 + ar * 64 + ac + 8) = x.v[1];
  };
  auto STAGEB = [&](int bf, int kt) {
#pragma unroll
    for (int i = 0; i < 2; ++i) {
      int o = i * 4096 + tid * 16;
      int r = o >> 7, c = (o & 127) >> 1;
      gll16(Bt + (size_t)r * 1024 + kt * 64 + c,
            (char*)Bs + bf * 8192 + i * 4096 + wave * 1024);
    }
  };

  f32x4 acc[2][2];
#pragma unroll
  for (int mi = 0; mi < 2; ++mi)
#pragma unroll
    for (int nj = 0; nj < 2; ++nj) acc[mi][nj] = f32x4{0.f, 0.f, 0.f, 0.f};

  f32x4 a4[4];
  LOADA(0, a4);
  STAGEB(0, 0);
  WRITEA(0, a4);
  __syncthreads();
  int cur = 0;
  for (int kt = 0; kt < 16; ++kt) {
    if (kt + 1 < 16) { LOADA(kt + 1, a4); STAGEB(cur ^ 1, kt + 1); }
#pragma unroll
    for (int ks = 0; ks < 2; ++ks) {
      s16x8 af[2]; s16x8 bf2[2];
#pragma unroll
      for (int mi = 0; mi < 2; ++mi)
        af[mi] = *(const s16x8*)(As + cur * 4096 + (wr * 32 + mi * 16 + l16) * 64 + ks * 32 + kq * 8);
#pragma unroll
      for (int nj = 0; nj < 2; ++nj)
        bf2[nj] = *(const s16x8*)(Bs + cur * 4096 + (wc * 32 + nj * 16 + l16) * 64 + ks * 32 + kq * 8);
#pragma unroll
      for (int mi = 0; mi < 2; ++mi)
#pragma unroll
        for (int nj = 0; nj < 2; ++nj)
          acc[mi][nj] = mfma16(af[mi], bf2[nj], acc[mi][nj]);
    }
    if (kt + 1 < 16) WRITEA(cur ^ 1, a4);   // vmcnt dep hidden under compute
    __syncthreads();
    cur ^= 1;
  }

  const float* bias = sel ? bv : bk;
#pragma unroll
  for (int mi = 0; mi < 2; ++mi)
#pragma unroll
  for (int nj = 0; nj < 2; ++nj) {
    int col = wc * 32 + nj * 16 + l16;
    int rowb = row0 + wr * 32 + mi * 16 + kq * 4;
    float bb = bias[col];
#pragma unroll
    for (int r = 0; r < 4; ++r) {
      int row = rowb + r;
      float val = acc[mi][nj][r] + bb;
      if (sel == 0)
        kproj[(size_t)row * 64 + col] = f2bf(val);
      else  // vprojT[b][d=col][n]
        vprojT[(size_t)(row >> 11) * 131072 + (size_t)col * 2048 + (row & 2047)] = f2bf(val);
    }
  }
}

// ---------------- merged qproj + kvproj launch (640 blocks, all co-resident) -
__global__ __launch_bounds__(256) void gemmqkv_kernel(
    const unsigned short* __restrict__ qbf, const unsigned short* __restrict__ WqT,
    const float* __restrict__ bq, unsigned short* __restrict__ qproj, float qscale,
    const float* __restrict__ key, const float* __restrict__ value,
    const unsigned short* __restrict__ WkT, const unsigned short* __restrict__ WvT,
    const float* __restrict__ bk, const float* __restrict__ bv,
    unsigned short* __restrict__ kproj, unsigned short* __restrict__ vprojT)
{
  __shared__ __align__(16) unsigned short SMEM[24576];   // 48KB union
  int bid = blockIdx.x;
  if (bid < 512) {
    gemm16_body<0>(qbf, WqT, bq, qproj, qscale, bid & 31, bid >> 5,
                   SMEM, SMEM + 16384);
  } else {
    int idx = bid - 512;                     // 0..127: 64 row-blocks x {k,v}
    gemmkv_body(key, value, WkT, WvT, bk, bv, kproj, vprojT,
                idx & 63, idx >> 6, SMEM, SMEM + 8192);
  }
}

// ---------------- out-proj launch ----------------
__global__ __launch_bounds__(256) void gemmout_kernel(
    const unsigned short* __restrict__ A, const unsigned short* __restrict__ Bt,
    const float* __restrict__ bias, float* __restrict__ Cpv)
{
  __shared__ __align__(16) unsigned short SMEM[24576];
  gemm16_body<2>(A, Bt, bias, (void*)Cpv, 1.0f, blockIdx.x, blockIdx.y,
                 SMEM, SMEM + 16384);
}

// ---------------- flash attention (MQA), swapped-operand 32x32 MFMA ---------
// Round 12: r10 proven numerics (defer-max, per-row mrun, scalar ssum) with
// ONE provably-equivalent micro: per-tile cross-half tsum shfl deferred to a
// single post-loop shfl (linear in ssum; alpha is hi-pair-uniform since tm is
// shfl-synced before the rescale decision).
__global__ __launch_bounds__(512, 4) void attn_kernel(
    const unsigned short* __restrict__ qp, const unsigned short* __restrict__ kp,
    const unsigned short* __restrict__ vpt, unsigned short* __restrict__ xout)
{
  constexpr int KSTR = 72;                   // 64 + 8 pad (shorts)
  __shared__ unsigned short SM[36864];
#define KBUF(c, hh) (SM + ((c) * 2 + (hh)) * (64 * KSTR))
#define VBUF(c, hh) (SM + 18432 + ((c) * 2 + (hh)) * (64 * KSTR))

  const int tid = threadIdx.x;
  const int lane = tid & 63, wave = tid >> 6;  // 8 waves
  const int lq = lane & 31, hi = lane >> 5;
  const int qsub = wave & 3, half = wave >> 2;
  const int b = blockIdx.y >> 4, h = blockIdx.y & 15;
  const int q0 = blockIdx.x * 128 + qsub * 32;
  const size_t qrow = (size_t)(b * 2048 + q0 + lq);

  s16x8 qf[4];  // Q as B-operand: lane holds Q[q][d = s*16 + 8*hi .. +8)
#pragma unroll
  for (int s = 0; s < 4; ++s)
    qf[s] = *(const s16x8*)(qp + qrow * 1024 + h * 64 + s * 16 + hi * 8);

  f32x16 xacc0 = zero16(), xacc1 = zero16();
  float mrun = -1e30f, ssum = 0.f;   // ssum: per-lane partial (own kv subset)

  const unsigned short* kb = kp + (size_t)b * (2048 * 64);
  const unsigned short* vb = vpt + (size_t)b * (64 * 2048);

  const int srow = tid >> 3;            // 0..63 (512 threads cover 64x64 tile)
  const int scol = (tid & 7) * 8;       // shorts; one 16B chunk per tile

  s16x8 kA, kB, vA, vB;
  {   // prologue: tiles 0 and 16 -> buf 0
    kA = *(const s16x8*)(kb + (size_t)srow * 64 + scol);
    kB = *(const s16x8*)(kb + (size_t)(16 * 64 + srow) * 64 + scol);
    vA = *(const s16x8*)(vb + (size_t)srow * 2048 + scol);
    vB = *(const s16x8*)(vb + (size_t)srow * 2048 + 16 * 64 + scol);
    *(s16x8*)(KBUF(0, 0) + srow * KSTR + scol) = kA;
    *(s16x8*)(KBUF(0, 1) + srow * KSTR + scol) = kB;
    *(s16x8*)(VBUF(0, 0) + srow * KSTR + scol) = vA;
    *(s16x8*)(VBUF(0, 1) + srow * KSTR + scol) = vB;
  }
  int cur = 0;

  for (int it = 0; it < 16; ++it) {
    __syncthreads();   // buf[cur] ready; buf[cur^1] free
    if (it + 1 < 16) { // issue next tile-pair loads (latency hidden under compute)
      kA = *(const s16x8*)(kb + (size_t)((it + 1) * 64 + srow) * 64 + scol);
      kB = *(const s16x8*)(kb + (size_t)((it + 17) * 64 + srow) * 64 + scol);
      vA = *(const s16x8*)(vb + (size_t)srow * 2048 + (it + 1) * 64 + scol);
      vB = *(const s16x8*)(vb + (size_t)srow * 2048 + (it + 17) * 64 + scol);
    }
    const unsigned short* Kc = KBUF(cur, half);
    const unsigned short* Vc = VBUF(cur, half);

    // S^T[kv][q], two 32-kv fragments
    f32x16 sacc0 = zero16(), sacc1 = zero16();
    __builtin_amdgcn_s_setprio(1);
#pragma unroll
    for (int s = 0; s < 4; ++s) {
      int c = s * 16 + hi * 8;
      s16x8 kf0 = *(const s16x8*)(Kc + lq * KSTR + c);
      s16x8 kf1 = *(const s16x8*)(Kc + (32 + lq) * KSTR + c);
      sacc0 = mfma32(kf0, qf[s], sacc0);
      sacc1 = mfma32(kf1, qf[s], sacc1);
    }
    __builtin_amdgcn_s_setprio(0);

    // online softmax, exp2 domain (scale folded into q-proj), defer-max THR=8
    float tm = fmaxf(max16_3(sacc0), max16_3(sacc1));
    tm = fmaxf(tm, __shfl_xor(tm, 32));
    if (!__all(tm <= mrun + 8.f)) {
      float mnew = fmaxf(mrun, tm);
      float alpha = __builtin_amdgcn_exp2f(mrun - mnew);
      ssum *= alpha;
#pragma unroll
      for (int e = 0; e < 16; ++e) { xacc0[e] *= alpha; xacc1[e] *= alpha; }
      mrun = mnew;
    }
    f32x16 p0, p1;
#pragma unroll
    for (int e = 0; e < 16; ++e) p0[e] = __builtin_amdgcn_exp2f(sacc0[e] - mrun);
#pragma unroll
    for (int e = 0; e < 16; ++e) p1[e] = __builtin_amdgcn_exp2f(sacc1[e] - mrun);
    ssum += sum16(p0) + sum16(p1);   // per-lane partial; combined post-loop

    // In-register P^T pack. Lane holds p[e] at kv=(e&3)+8*(e>>2)+4*hi (+32 p1).
    s16x8 pb[4];
#pragma unroll
    for (int grp = 0; grp < 4; ++grp) {       // grp: {p0,p1} x {e0-7, e8-15}
      const f32x16& pp = (grp < 2) ? p0 : p1;
      const int eb = (grp & 1) * 8;
      unsigned A  = cvtpk(pp[eb + 0], pp[eb + 1]);
      unsigned Bw = cvtpk(pp[eb + 2], pp[eb + 3]);
      unsigned Cw = cvtpk(pp[eb + 4], pp[eb + 5]);
      unsigned Dw = cvtpk(pp[eb + 6], pp[eb + 7]);
      unsigned rA = (unsigned)__shfl_xor((int)(hi ? A : Cw), 32);
      unsigned rB = (unsigned)__shfl_xor((int)(hi ? Bw : Dw), 32);
      union { unsigned u[4]; s16x8 v; } pk_;
      pk_.u[0] = hi ? rA : A;
      pk_.u[1] = hi ? rB : Bw;
      pk_.u[2] = hi ? Cw : rA;
      pk_.u[3] = hi ? Dw : rB;
      pb[grp] = pk_.v;
    }

    // X^T += V^T @ P^T  (two 32-d fragments)
    __builtin_amdgcn_s_setprio(1);
#pragma unroll
    for (int kvs = 0; kvs < 4; ++kvs) {
      int c = kvs * 16 + hi * 8;
      s16x8 vf0 = *(const s16x8*)(Vc + lq * KSTR + c);
      s16x8 vf1 = *(const s16x8*)(Vc + (32 + lq) * KSTR + c);
      xacc0 = mfma32(vf0, pb[kvs], xacc0);
      xacc1 = mfma32(vf1, pb[kvs], xacc1);
    }
    __builtin_amdgcn_s_setprio(0);

    if (it + 1 < 16) {  // write staged regs -> other buffer
      *(s16x8*)(KBUF(cur ^ 1, 0) + srow * KSTR + scol) = kA;
      *(s16x8*)(KBUF(cur ^ 1, 1) + srow * KSTR + scol) = kB;
      *(s16x8*)(VBUF(cur ^ 1, 0) + srow * KSTR + scol) = vA;
      *(s16x8*)(VBUF(cur ^ 1, 1) + srow * KSTR + scol) = vB;
      cur ^= 1;
    }
  }
  ssum += __shfl_xor(ssum, 32);        // combine hi-pair partials once

  // ---- merge the two kv-halves (pair: waves qsub & qsub+4), via LDS ----
  __syncthreads();                     // all K/V reads done; SM reusable
  float* msc = (float*)SM;             // stride 37 f32 per lane
  const int mi_ = (qsub * 64 + lane) * 37;
  if (half == 1) {
#pragma unroll
    for (int e = 0; e < 16; ++e) { msc[mi_ + e] = xacc0[e]; msc[mi_ + 16 + e] = xacc1[e]; }
    msc[mi_ + 32] = mrun;
    msc[mi_ + 33] = ssum;
  }
  __syncthreads();
  if (half == 0) {
    float pm = msc[mi_ + 32], ps = msc[mi_ + 33];
    float mf = fmaxf(mrun, pm);
    float aa = __builtin_amdgcn_exp2f(mrun - mf);
    float bb = __builtin_amdgcn_exp2f(pm - mf);
    float inv = 1.0f / (ssum * aa + ps * bb);
#pragma unroll
    for (int dj = 0; dj < 2; ++dj) {
      const f32x16 xa = dj ? xacc1 : xacc0;
#pragma unroll
      for (int g = 0; g < 4; ++g) {
        u16x4 o4;
#pragma unroll
        for (int r = 0; r < 4; ++r) {
          int e = g * 4 + r;
          float merged = xa[e] * aa + msc[mi_ + dj * 16 + e] * bb;
          o4[r] = f2bf(merged * inv);
        }
        int d0 = dj * 32 + 8 * g + 4 * hi;
        *(u16x4*)(xout + qrow * 1024 + h * 64 + d0) = o4;
      }
    }
  }
#undef KBUF
#undef VBUF
}

// -----------------------------------------------------------------------------
extern "C" void kernel_launch(void* const* d_in, const int* in_sizes, int n_in,
                              void* d_out, int out_size, void* d_ws, size_t ws_size,
                              hipStream_t stream)
{
  const float* query = (const float*)d_in[0];
  const float* key   = (const float*)d_in[1];
  const float* value = (const float*)d_in[2];
  const float* Wq = (const float*)d_in[4];
  const float* bq = (const float*)d_in[5];
  const float* Wk = (const float*)d_in[6];
  const float* bk = (const float*)d_in[7];
  const float* Wv = (const float*)d_in[8];
  const float* bv = (const float*)d_in[9];
  const float* Wp = (const float*)d_in[10];
  const float* bp = (const float*)d_in[11];

  char* ws = (char*)d_ws;
  unsigned short* WqT    = (unsigned short*)(ws);
  unsigned short* WpT    = (unsigned short*)(ws + (2u << 20));
  unsigned short* WkT    = (unsigned short*)(ws + (4u << 20));
  unsigned short* WvT    = (unsigned short*)(ws + (4u << 20) + (128u << 10));
  unsigned short* kproj  = (unsigned short*)(ws + (5u << 20));
  unsigned short* vprojT = (unsigned short*)(ws + (5u << 20) + (512u << 10));
  unsigned short* qproj  = (unsigned short*)(ws + (6u << 20));     // 8.39MB
  unsigned short* xbuf   = (unsigned short*)(ws + (15u << 20));    // 8.39MB
  unsigned short* qbf    = (unsigned short*)d_out;                  // dead until out-proj

  prep_kernel<<<dim3(3136), 256, 0, stream>>>(
      query, qbf, Wq, Wk, Wv, Wp, WqT, WkT, WvT, WpT);

  const float qscale = 0.18033688011112042f;  // hd^-0.5 * log2(e)
  gemmqkv_kernel<<<dim3(640), 256, 0, stream>>>(
      qbf, WqT, bq, qproj, qscale, key, value, WkT, WvT, bk, bv, kproj, vprojT);
  attn_kernel<<<dim3(16, 32), 512, 0, stream>>>(qproj, kproj, vprojT, xbuf);
  gemmout_kernel<<<dim3(32, 16), 256, 0, stream>>>(xbuf, WpT, bp, (float*)d_out);
}

// Round 13
// 103.976 us; speedup vs baseline: 1.0433x; 1.0433x over previous
//
#include <hip/hip_runtime.h>
#include <hip/hip_bf16.h>

#define DI __device__ __forceinline__

typedef float f32x4 __attribute__((ext_vector_type(4)));
typedef float f32x16 __attribute__((ext_vector_type(16)));
typedef short s16x8 __attribute__((ext_vector_type(8)));
typedef unsigned short u16x4 __attribute__((ext_vector_type(4)));
typedef unsigned long long u64;

// Problem constants: N=2048, B=2, C=1024, H=16, HD=64, M=B*N=4096.

DI unsigned short f2bf(float x) {            // f32 -> bf16 RNE (epilogue use)
  union { float f; unsigned u; } v; v.f = x;
  unsigned r = 0x7fffu + ((v.u >> 16) & 1u);
  return (unsigned short)((v.u + r) >> 16);
}

DI unsigned cvtpk(float lo, float hi) {      // packed f32x2 -> bf16x2 (RNE)
  unsigned u;
  asm("v_cvt_pk_bf16_f32 %0, %1, %2" : "=v"(u) : "v"(lo), "v"(hi));
  return u;
}

DI float max3f(float a, float b, float c) {
  float d;
  asm("v_max3_f32 %0, %1, %2, %3" : "=v"(d) : "v"(a), "v"(b), "v"(c));
  return d;
}

DI f32x16 zero16() {
  f32x16 z;
#pragma unroll
  for (int i = 0; i < 16; ++i) z[i] = 0.f;
  return z;
}

DI float max16_3(const f32x16& a) {          // max3 tree: 8 instrs
  float m0 = max3f(a[0], a[1], a[2]);
  float m1 = max3f(a[3], a[4], a[5]);
  float m2 = max3f(a[6], a[7], a[8]);
  float m3 = max3f(a[9], a[10], a[11]);
  float m4 = max3f(a[12], a[13], a[14]);
  float n0 = max3f(m0, m1, m2);
  float n1 = max3f(m3, m4, a[15]);
  return fmaxf(n0, n1);
}

DI float sum16(const f32x16& a) {            // 4-level tree
  float s0 = a[0] + a[1],  s1 = a[2] + a[3];
  float s2 = a[4] + a[5],  s3 = a[6] + a[7];
  float s4 = a[8] + a[9],  s5 = a[10] + a[11];
  float s6 = a[12] + a[13], s7 = a[14] + a[15];
  s0 += s1; s2 += s3; s4 += s5; s6 += s7;
  return (s0 + s2) + (s4 + s6);
}

DI void gll16(const void* g, void* l) {      // async global->LDS, 16B/lane
  __builtin_amdgcn_global_load_lds(
      (const __attribute__((address_space(1))) void*)g,
      (__attribute__((address_space(3))) void*)l, 16, 0, 0);
}

DI f32x16 mfma32(s16x8 a, s16x8 b, f32x16 c) {
  return __builtin_amdgcn_mfma_f32_32x32x16_bf16(a, b, c, 0, 0, 0);
}

DI f32x4 mfma16(s16x8 a, s16x8 b, f32x4 c) {
  return __builtin_amdgcn_mfma_f32_16x16x32_bf16(a, b, c, 0, 0, 0);
}

// ---------------- prep: weight transpose/convert + query cvt ----------------
// bid<2048: qbf[row=b*2048+n][c]=bf16(query[n][b][c]); else wconv (1088 tiles).
__global__ __launch_bounds__(256) void prep_kernel(
    const float* __restrict__ q, unsigned short* __restrict__ qbf,
    const float* __restrict__ Wq, const float* __restrict__ Wk,
    const float* __restrict__ Wv, const float* __restrict__ Wp,
    unsigned short* __restrict__ WqT, unsigned short* __restrict__ WkT,
    unsigned short* __restrict__ WvT, unsigned short* __restrict__ WpT)
{
  int bid = blockIdx.x;
  if (bid < 2048) {
    int gid = bid * 256 + threadIdx.x;    // 524288
    int row = gid >> 7;
    int c8 = (gid & 127) << 3;
    int b = row >> 11, n = row & 2047;
    size_t soff = ((size_t)n * 2 + b) * 1024 + c8;
    f32x4 v0 = *(const f32x4*)(q + soff);
    f32x4 v1 = *(const f32x4*)(q + soff + 4);
    union { unsigned u[4]; s16x8 v; } x;
    x.u[0] = cvtpk(v0.x, v0.y); x.u[1] = cvtpk(v0.z, v0.w);
    x.u[2] = cvtpk(v1.x, v1.y); x.u[3] = cvtpk(v1.z, v1.w);
    *(s16x8*)(qbf + (size_t)row * 1024 + c8) = x.v;
    return;
  }
  int wb = bid - 2048;
  const float* W; unsigned short* WT; int Ncols; int base;
  if (wb < 512)       { W = Wq; WT = WqT; Ncols = 1024; base = wb; }
  else if (wb < 1024) { W = Wp; WT = WpT; Ncols = 1024; base = wb - 512; }
  else if (wb < 1056) { W = Wk; WT = WkT; Ncols = 64;   base = wb - 1024; }
  else                { W = Wv; WT = WvT; Ncols = 64;   base = wb - 1056; }
  int nb = base >> 5, kb = base & 31;              // 64-n x 32-k tile
  int n = nb * 64 + (threadIdx.x & 63);
  int k = kb * 32 + (threadIdx.x >> 6) * 8;
  float f[8];
#pragma unroll
  for (int i = 0; i < 8; ++i) f[i] = W[(size_t)(k + i) * Ncols + n];
  union { unsigned u[4]; s16x8 v; } x;
#pragma unroll
  for (int i = 0; i < 4; ++i) x.u[i] = cvtpk(f[2 * i], f[2 * i + 1]);
  *(s16x8*)(WT + (size_t)n * 1024 + k) = x.v;
}

// ---------------- GEMM16 body (bf16 A via gll, prefetch dbuf): BM=128,BN=64 -
// MODE 0: qproj (out bf16 * scale).  MODE 2: out-proj (f32, (N,B,C) remap).
// As: 2 bufs x 8192 shorts; Bs: 2 bufs x 4096 shorts.
template<int MODE>
DI void gemm16_body(const unsigned short* __restrict__ A,
                    const unsigned short* __restrict__ Bt,
                    const float* __restrict__ bias, void* __restrict__ Cpv,
                    float scale, int bx, int by,
                    unsigned short* As, unsigned short* Bs)
{
  const int tid = threadIdx.x;
  const int lane = tid & 63, wave = tid >> 6;
  const int l16 = lane & 15, kq = lane >> 4;
  const int wr = wave >> 1, wc = wave & 1;   // WROWS=64, WCOLS=32; MI=4, NJ=2
  const int row0 = bx * 128;
  const int col0 = by * 64;

  f32x4 acc[4][2];
#pragma unroll
  for (int mi = 0; mi < 4; ++mi)
#pragma unroll
    for (int nj = 0; nj < 2; ++nj) acc[mi][nj] = f32x4{0.f, 0.f, 0.f, 0.f};

  auto STAGE = [&](int bf, int kt) {
    const int k0 = kt * 64;
    char* Ad = (char*)As + bf * 16384;
    char* Bd = (char*)Bs + bf * 8192;
#pragma unroll
    for (int i = 0; i < 4; ++i) {
      int o = i * 4096 + tid * 16;
      int r = o >> 7, c = (o & 127) >> 1;
      gll16(A + (size_t)(row0 + r) * 1024 + k0 + c, Ad + i * 4096 + wave * 1024);
    }
#pragma unroll
    for (int i = 0; i < 2; ++i) {
      int o = i * 4096 + tid * 16;
      int r = o >> 7, c = (o & 127) >> 1;
      gll16(Bt + (size_t)(col0 + r) * 1024 + k0 + c, Bd + i * 4096 + wave * 1024);
    }
  };

  STAGE(0, 0);
  __syncthreads();                 // implicit vmcnt(0) drain -> buf0 ready
  int cur = 0;
  for (int kt = 0; kt < 16; ++kt) {
    if (kt + 1 < 16) STAGE(cur ^ 1, kt + 1);   // prefetch next (hidden)
#pragma unroll
    for (int ks = 0; ks < 2; ++ks) {
      s16x8 af[4]; s16x8 bf2[2];
#pragma unroll
      for (int mi = 0; mi < 4; ++mi)
        af[mi] = *(const s16x8*)(As + cur * 8192 + (wr * 64 + mi * 16 + l16) * 64 + ks * 32 + kq * 8);
#pragma unroll
      for (int nj = 0; nj < 2; ++nj)
        bf2[nj] = *(const s16x8*)(Bs + cur * 4096 + (wc * 32 + nj * 16 + l16) * 64 + ks * 32 + kq * 8);
#pragma unroll
      for (int mi = 0; mi < 4; ++mi)
#pragma unroll
        for (int nj = 0; nj < 2; ++nj)
          acc[mi][nj] = mfma16(af[mi], bf2[nj], acc[mi][nj]);
    }
    __syncthreads();               // drains prefetch vmcnt + guards buf reuse
    cur ^= 1;
  }

  // epilogue; 16x16 C/D: col=lane&15, row=(lane>>4)*4 + r  [m89-verified]
#pragma unroll
  for (int mi = 0; mi < 4; ++mi)
#pragma unroll
  for (int nj = 0; nj < 2; ++nj) {
    int col = col0 + wc * 32 + nj * 16 + l16;
    int rowb = row0 + wr * 64 + mi * 16 + kq * 4;
    float bv = bias[col];
#pragma unroll
    for (int r = 0; r < 4; ++r) {
      int row = rowb + r;
      float val = acc[mi][nj][r] + bv;
      if constexpr (MODE == 0) {
        ((unsigned short*)Cpv)[(size_t)row * 1024 + col] = f2bf(val * scale);
      } else {
        ((float*)Cpv)[(size_t)(row & 2047) * 2048 + (size_t)(row >> 11) * 1024 + col] = val;
      }
    }
  }
}

// ---------------- kv-proj body: A = key/value f32 (reg-staged), FULL K ------
// Writes kproj / vprojT directly (+bias). As/Bs: 2 bufs x 4096 shorts each.
DI void gemmkv_body(const float* __restrict__ Akey, const float* __restrict__ Aval,
                    const unsigned short* __restrict__ Wk,
                    const unsigned short* __restrict__ Wv,
                    const float* __restrict__ bk, const float* __restrict__ bv,
                    unsigned short* __restrict__ kproj,
                    unsigned short* __restrict__ vprojT,
                    int bx, int sel,
                    unsigned short* As, unsigned short* Bs)
{
  const int tid = threadIdx.x;
  const int lane = tid & 63, wave = tid >> 6;
  const int l16 = lane & 15, kq = lane >> 4;
  const int wr = wave >> 1, wc = wave & 1;   // WROWS=32, WCOLS=32; MI=2, NJ=2
  const float* Af = sel ? Aval : Akey;
  const unsigned short* Bt = sel ? Wv : Wk;
  const int row0 = bx * 64;

  const int ar = tid >> 2, ac = (tid & 3) * 16;     // A: row 0..63, 16 f32/thread
  const int gm = row0 + ar;
  const size_t grow = sel ? (size_t)gm * 1024
                          : (size_t)((gm & 2047) * 2 + (gm >> 11)) * 1024;  // key remap

  auto LOADA = [&](int kt, f32x4* a4) {
#pragma unroll
    for (int i = 0; i < 4; ++i)
      a4[i] = *(const f32x4*)(Af + grow + kt * 64 + ac + i * 4);
  };
  auto WRITEA = [&](int bf, const f32x4* a4) {
    union { unsigned u[8]; s16x8 v[2]; } x;
#pragma unroll
    for (int i = 0; i < 4; ++i) {
      x.u[2 * i]     = cvtpk(a4[i].x, a4[i].y);
      x.u[2 * i + 1] = cvtpk(a4[i].z, a4[i].w);
    }
    *(s16x8*)(As + bf * 4096 + ar * 64 + ac)     = x.v[0];
    *(s16x8*)(As + bf * 4096 + ar * 64 + ac + 8) = x.v[1];
  };
  auto STAGEB = [&](int bf, int kt) {
#pragma unroll
    for (int i = 0; i < 2; ++i) {
      int o = i * 4096 + tid * 16;
      int r = o >> 7, c = (o & 127) >> 1;
      gll16(Bt + (size_t)r * 1024 + kt * 64 + c,
            (char*)Bs + bf * 8192 + i * 4096 + wave * 1024);
    }
  };

  f32x4 acc[2][2];
#pragma unroll
  for (int mi = 0; mi < 2; ++mi)
#pragma unroll
    for (int nj = 0; nj < 2; ++nj) acc[mi][nj] = f32x4{0.f, 0.f, 0.f, 0.f};

  f32x4 a4[4];
  LOADA(0, a4);
  STAGEB(0, 0);
  WRITEA(0, a4);
  __syncthreads();
  int cur = 0;
  for (int kt = 0; kt < 16; ++kt) {
    if (kt + 1 < 16) { LOADA(kt + 1, a4); STAGEB(cur ^ 1, kt + 1); }
#pragma unroll
    for (int ks = 0; ks < 2; ++ks) {
      s16x8 af[2]; s16x8 bf2[2];
#pragma unroll
      for (int mi = 0; mi < 2; ++mi)
        af[mi] = *(const s16x8*)(As + cur * 4096 + (wr * 32 + mi * 16 + l16) * 64 + ks * 32 + kq * 8);
#pragma unroll
      for (int nj = 0; nj < 2; ++nj)
        bf2[nj] = *(const s16x8*)(Bs + cur * 4096 + (wc * 32 + nj * 16 + l16) * 64 + ks * 32 + kq * 8);
#pragma unroll
      for (int mi = 0; mi < 2; ++mi)
#pragma unroll
        for (int nj = 0; nj < 2; ++nj)
          acc[mi][nj] = mfma16(af[mi], bf2[nj], acc[mi][nj]);
    }
    if (kt + 1 < 16) WRITEA(cur ^ 1, a4);   // vmcnt dep hidden under compute
    __syncthreads();
    cur ^= 1;
  }

  const float* bias = sel ? bv : bk;
#pragma unroll
  for (int mi = 0; mi < 2; ++mi)
#pragma unroll
  for (int nj = 0; nj < 2; ++nj) {
    int col = wc * 32 + nj * 16 + l16;
    int rowb = row0 + wr * 32 + mi * 16 + kq * 4;
    float bb = bias[col];
#pragma unroll
    for (int r = 0; r < 4; ++r) {
      int row = rowb + r;
      float val = acc[mi][nj][r] + bb;
      if (sel == 0)
        kproj[(size_t)row * 64 + col] = f2bf(val);
      else  // vprojT[b][d=col][n]
        vprojT[(size_t)(row >> 11) * 131072 + (size_t)col * 2048 + (row & 2047)] = f2bf(val);
    }
  }
}

// ---------------- merged qproj + kvproj launch (640 blocks, all co-resident) -
__global__ __launch_bounds__(256) void gemmqkv_kernel(
    const unsigned short* __restrict__ qbf, const unsigned short* __restrict__ WqT,
    const float* __restrict__ bq, unsigned short* __restrict__ qproj, float qscale,
    const float* __restrict__ key, const float* __restrict__ value,
    const unsigned short* __restrict__ WkT, const unsigned short* __restrict__ WvT,
    const float* __restrict__ bk, const float* __restrict__ bv,
    unsigned short* __restrict__ kproj, unsigned short* __restrict__ vprojT)
{
  __shared__ __align__(16) unsigned short SMEM[24576];   // 48KB union
  int bid = blockIdx.x;
  if (bid < 512) {
    gemm16_body<0>(qbf, WqT, bq, qproj, qscale, bid & 31, bid >> 5,
                   SMEM, SMEM + 16384);
  } else {
    int idx = bid - 512;                     // 0..127: 64 row-blocks x {k,v}
    gemmkv_body(key, value, WkT, WvT, bk, bv, kproj, vprojT,
                idx & 63, idx >> 6, SMEM, SMEM + 8192);
  }
}

// ---------------- out-proj launch ----------------
__global__ __launch_bounds__(256) void gemmout_kernel(
    const unsigned short* __restrict__ A, const unsigned short* __restrict__ Bt,
    const float* __restrict__ bias, float* __restrict__ Cpv)
{
  __shared__ __align__(16) unsigned short SMEM[24576];
  gemm16_body<2>(A, Bt, bias, (void*)Cpv, 1.0f, blockIdx.x, blockIdx.y,
                 SMEM, SMEM + 16384);
}

// ---------------- flash attention (MQA), swapped-operand 32x32 MFMA ---------
// Round 13: r10 attn BYTE-EXACT (measured 56.4us, VGPR 64, no spill).
// Per-tile tsum shfl RESTORED — r12's deferred-ssum triggered scratch spill
// (FETCH/WRITE +11MB, +8us) despite being numerically equivalent.
__global__ __launch_bounds__(512, 4) void attn_kernel(
    const unsigned short* __restrict__ qp, const unsigned short* __restrict__ kp,
    const unsigned short* __restrict__ vpt, unsigned short* __restrict__ xout)
{
  constexpr int KSTR = 72;                   // 64 + 8 pad (shorts)
  __shared__ unsigned short SM[36864];
#define KBUF(c, hh) (SM + ((c) * 2 + (hh)) * (64 * KSTR))
#define VBUF(c, hh) (SM + 18432 + ((c) * 2 + (hh)) * (64 * KSTR))

  const int tid = threadIdx.x;
  const int lane = tid & 63, wave = tid >> 6;  // 8 waves
  const int lq = lane & 31, hi = lane >> 5;
  const int qsub = wave & 3, half = wave >> 2;
  const int b = blockIdx.y >> 4, h = blockIdx.y & 15;
  const int q0 = blockIdx.x * 128 + qsub * 32;
  const size_t qrow = (size_t)(b * 2048 + q0 + lq);

  s16x8 qf[4];  // Q as B-operand: lane holds Q[q][d = s*16 + 8*hi .. +8)
#pragma unroll
  for (int s = 0; s < 4; ++s)
    qf[s] = *(const s16x8*)(qp + qrow * 1024 + h * 64 + s * 16 + hi * 8);

  f32x16 xacc0 = zero16(), xacc1 = zero16();
  float mrun = -1e30f, ssum = 0.f;

  const unsigned short* kb = kp + (size_t)b * (2048 * 64);
  const unsigned short* vb = vpt + (size_t)b * (64 * 2048);

  const int srow = tid >> 3;            // 0..63 (512 threads cover 64x64 tile)
  const int scol = (tid & 7) * 8;       // shorts; one 16B chunk per tile

  s16x8 kA, kB, vA, vB;
  {   // prologue: tiles 0 and 16 -> buf 0
    kA = *(const s16x8*)(kb + (size_t)srow * 64 + scol);
    kB = *(const s16x8*)(kb + (size_t)(16 * 64 + srow) * 64 + scol);
    vA = *(const s16x8*)(vb + (size_t)srow * 2048 + scol);
    vB = *(const s16x8*)(vb + (size_t)srow * 2048 + 16 * 64 + scol);
    *(s16x8*)(KBUF(0, 0) + srow * KSTR + scol) = kA;
    *(s16x8*)(KBUF(0, 1) + srow * KSTR + scol) = kB;
    *(s16x8*)(VBUF(0, 0) + srow * KSTR + scol) = vA;
    *(s16x8*)(VBUF(0, 1) + srow * KSTR + scol) = vB;
  }
  int cur = 0;

  for (int it = 0; it < 16; ++it) {
    __syncthreads();   // buf[cur] ready; buf[cur^1] free
    if (it + 1 < 16) { // issue next tile-pair loads (latency hidden under compute)
      kA = *(const s16x8*)(kb + (size_t)((it + 1) * 64 + srow) * 64 + scol);
      kB = *(const s16x8*)(kb + (size_t)((it + 17) * 64 + srow) * 64 + scol);
      vA = *(const s16x8*)(vb + (size_t)srow * 2048 + (it + 1) * 64 + scol);
      vB = *(const s16x8*)(vb + (size_t)srow * 2048 + (it + 17) * 64 + scol);
    }
    const unsigned short* Kc = KBUF(cur, half);
    const unsigned short* Vc = VBUF(cur, half);

    // S^T[kv][q], two 32-kv fragments
    f32x16 sacc0 = zero16(), sacc1 = zero16();
    __builtin_amdgcn_s_setprio(1);
#pragma unroll
    for (int s = 0; s < 4; ++s) {
      int c = s * 16 + hi * 8;
      s16x8 kf0 = *(const s16x8*)(Kc + lq * KSTR + c);
      s16x8 kf1 = *(const s16x8*)(Kc + (32 + lq) * KSTR + c);
      sacc0 = mfma32(kf0, qf[s], sacc0);
      sacc1 = mfma32(kf1, qf[s], sacc1);
    }
    __builtin_amdgcn_s_setprio(0);

    // online softmax, exp2 domain (scale folded into q-proj), defer-max THR=8
    float tm = fmaxf(max16_3(sacc0), max16_3(sacc1));
    tm = fmaxf(tm, __shfl_xor(tm, 32));
    if (!__all(tm <= mrun + 8.f)) {
      float mnew = fmaxf(mrun, tm);
      float alpha = __builtin_amdgcn_exp2f(mrun - mnew);
      ssum *= alpha;
#pragma unroll
      for (int e = 0; e < 16; ++e) { xacc0[e] *= alpha; xacc1[e] *= alpha; }
      mrun = mnew;
    }
    f32x16 p0, p1;
#pragma unroll
    for (int e = 0; e < 16; ++e) p0[e] = __builtin_amdgcn_exp2f(sacc0[e] - mrun);
#pragma unroll
    for (int e = 0; e < 16; ++e) p1[e] = __builtin_amdgcn_exp2f(sacc1[e] - mrun);
    float tsum = sum16(p0) + sum16(p1);
    tsum += __shfl_xor(tsum, 32);
    ssum += tsum;

    // In-register P^T pack. Lane holds p[e] at kv=(e&3)+8*(e>>2)+4*hi (+32 p1).
    s16x8 pb[4];
#pragma unroll
    for (int grp = 0; grp < 4; ++grp) {       // grp: {p0,p1} x {e0-7, e8-15}
      const f32x16& pp = (grp < 2) ? p0 : p1;
      const int eb = (grp & 1) * 8;
      unsigned A  = cvtpk(pp[eb + 0], pp[eb + 1]);
      unsigned Bw = cvtpk(pp[eb + 2], pp[eb + 3]);
      unsigned Cw = cvtpk(pp[eb + 4], pp[eb + 5]);
      unsigned Dw = cvtpk(pp[eb + 6], pp[eb + 7]);
      unsigned rA = (unsigned)__shfl_xor((int)(hi ? A : Cw), 32);
      unsigned rB = (unsigned)__shfl_xor((int)(hi ? Bw : Dw), 32);
      union { unsigned u[4]; s16x8 v; } pk_;
      pk_.u[0] = hi ? rA : A;
      pk_.u[1] = hi ? rB : Bw;
      pk_.u[2] = hi ? Cw : rA;
      pk_.u[3] = hi ? Dw : rB;
      pb[grp] = pk_.v;
    }

    // X^T += V^T @ P^T  (two 32-d fragments)
    __builtin_amdgcn_s_setprio(1);
#pragma unroll
    for (int kvs = 0; kvs < 4; ++kvs) {
      int c = kvs * 16 + hi * 8;
      s16x8 vf0 = *(const s16x8*)(Vc + lq * KSTR + c);
      s16x8 vf1 = *(const s16x8*)(Vc + (32 + lq) * KSTR + c);
      xacc0 = mfma32(vf0, pb[kvs], xacc0);
      xacc1 = mfma32(vf1, pb[kvs], xacc1);
    }
    __builtin_amdgcn_s_setprio(0);

    if (it + 1 < 16) {  // write staged regs -> other buffer
      *(s16x8*)(KBUF(cur ^ 1, 0) + srow * KSTR + scol) = kA;
      *(s16x8*)(KBUF(cur ^ 1, 1) + srow * KSTR + scol) = kB;
      *(s16x8*)(VBUF(cur ^ 1, 0) + srow * KSTR + scol) = vA;
      *(s16x8*)(VBUF(cur ^ 1, 1) + srow * KSTR + scol) = vB;
      cur ^= 1;
    }
  }

  // ---- merge the two kv-halves (pair: waves qsub & qsub+4), via LDS ----
  __syncthreads();                     // all K/V reads done; SM reusable
  float* msc = (float*)SM;             // stride 37 f32 per lane
  const int mi_ = (qsub * 64 + lane) * 37;
  if (half == 1) {
#pragma unroll
    for (int e = 0; e < 16; ++e) { msc[mi_ + e] = xacc0[e]; msc[mi_ + 16 + e] = xacc1[e]; }
    msc[mi_ + 32] = mrun;
    msc[mi_ + 33] = ssum;
  }
  __syncthreads();
  if (half == 0) {
    float pm = msc[mi_ + 32], ps = msc[mi_ + 33];
    float mf = fmaxf(mrun, pm);
    float aa = __builtin_amdgcn_exp2f(mrun - mf);
    float bb = __builtin_amdgcn_exp2f(pm - mf);
    float inv = 1.0f / (ssum * aa + ps * bb);
#pragma unroll
    for (int dj = 0; dj < 2; ++dj) {
      const f32x16 xa = dj ? xacc1 : xacc0;
#pragma unroll
      for (int g = 0; g < 4; ++g) {
        u16x4 o4;
#pragma unroll
        for (int r = 0; r < 4; ++r) {
          int e = g * 4 + r;
          float merged = xa[e] * aa + msc[mi_ + dj * 16 + e] * bb;
          o4[r] = f2bf(merged * inv);
        }
        int d0 = dj * 32 + 8 * g + 4 * hi;
        *(u16x4*)(xout + qrow * 1024 + h * 64 + d0) = o4;
      }
    }
  }
#undef KBUF
#undef VBUF
}

// -----------------------------------------------------------------------------
extern "C" void kernel_launch(void* const* d_in, const int* in_sizes, int n_in,
                              void* d_out, int out_size, void* d_ws, size_t ws_size,
                              hipStream_t stream)
{
  const float* query = (const float*)d_in[0];
  const float* key   = (const float*)d_in[1];
  const float* value = (const float*)d_in[2];
  const float* Wq = (const float*)d_in[4];
  const float* bq = (const float*)d_in[5];
  const float* Wk = (const float*)d_in[6];
  const float* bk = (const float*)d_in[7];
  const float* Wv = (const float*)d_in[8];
  const float* bv = (const float*)d_in[9];
  const float* Wp = (const float*)d_in[10];
  const float* bp = (const float*)d_in[11];

  char* ws = (char*)d_ws;
  unsigned short* WqT    = (unsigned short*)(ws);
  unsigned short* WpT    = (unsigned short*)(ws + (2u << 20));
  unsigned short* WkT    = (unsigned short*)(ws + (4u << 20));
  unsigned short* WvT    = (unsigned short*)(ws + (4u << 20) + (128u << 10));
  unsigned short* kproj  = (unsigned short*)(ws + (5u << 20));
  unsigned short* vprojT = (unsigned short*)(ws + (5u << 20) + (512u << 10));
  unsigned short* qproj  = (unsigned short*)(ws + (6u << 20));     // 8.39MB
  unsigned short* xbuf   = (unsigned short*)(ws + (15u << 20));    // 8.39MB
  unsigned short* qbf    = (unsigned short*)d_out;                  // dead until out-proj

  prep_kernel<<<dim3(3136), 256, 0, stream>>>(
      query, qbf, Wq, Wk, Wv, Wp, WqT, WkT, WvT, WpT);

  const float qscale = 0.18033688011112042f;  // hd^-0.5 * log2(e)
  gemmqkv_kernel<<<dim3(640), 256, 0, stream>>>(
      qbf, WqT, bq, qproj, qscale, key, value, WkT, WvT, bk, bv, kproj, vprojT);
  attn_kernel<<<dim3(16, 32), 512, 0, stream>>>(qproj, kproj, vprojT, xbuf);
  gemmout_kernel<<<dim3(32, 16), 256, 0, stream>>>(xbuf, WpT, bp, (float*)d_out);
}

// Round 14
// 101.407 us; speedup vs baseline: 1.0698x; 1.0253x over previous
//
#include <hip/hip_runtime.h>
#include <hip/hip_bf16.h>

#define DI __device__ __forceinline__

typedef float f32x4 __attribute__((ext_vector_type(4)));
typedef float f32x16 __attribute__((ext_vector_type(16)));
typedef short s16x8 __attribute__((ext_vector_type(8)));
typedef unsigned short u16x4 __attribute__((ext_vector_type(4)));
typedef unsigned long long u64;

// Problem constants: N=2048, B=2, C=1024, H=16, HD=64, M=B*N=4096.

DI unsigned short f2bf(float x) {            // f32 -> bf16 RNE (epilogue use)
  union { float f; unsigned u; } v; v.f = x;
  unsigned r = 0x7fffu + ((v.u >> 16) & 1u);
  return (unsigned short)((v.u + r) >> 16);
}

DI unsigned cvtpk(float lo, float hi) {      // packed f32x2 -> bf16x2 (RNE)
  unsigned u;
  asm("v_cvt_pk_bf16_f32 %0, %1, %2" : "=v"(u) : "v"(lo), "v"(hi));
  return u;
}

DI float max3f(float a, float b, float c) {
  float d;
  asm("v_max3_f32 %0, %1, %2, %3" : "=v"(d) : "v"(a), "v"(b), "v"(c));
  return d;
}

DI f32x16 zero16() {
  f32x16 z;
#pragma unroll
  for (int i = 0; i < 16; ++i) z[i] = 0.f;
  return z;
}

DI float max16_3(const f32x16& a) {          // max3 tree: 8 instrs
  float m0 = max3f(a[0], a[1], a[2]);
  float m1 = max3f(a[3], a[4], a[5]);
  float m2 = max3f(a[6], a[7], a[8]);
  float m3 = max3f(a[9], a[10], a[11]);
  float m4 = max3f(a[12], a[13], a[14]);
  float n0 = max3f(m0, m1, m2);
  float n1 = max3f(m3, m4, a[15]);
  return fmaxf(n0, n1);
}

DI float sum16(const f32x16& a) {            // 4-level tree
  float s0 = a[0] + a[1],  s1 = a[2] + a[3];
  float s2 = a[4] + a[5],  s3 = a[6] + a[7];
  float s4 = a[8] + a[9],  s5 = a[10] + a[11];
  float s6 = a[12] + a[13], s7 = a[14] + a[15];
  s0 += s1; s2 += s3; s4 += s5; s6 += s7;
  return (s0 + s2) + (s4 + s6);
}

DI void gll16(const void* g, void* l) {      // async global->LDS, 16B/lane
  __builtin_amdgcn_global_load_lds(
      (const __attribute__((address_space(1))) void*)g,
      (__attribute__((address_space(3))) void*)l, 16, 0, 0);
}

DI f32x16 mfma32(s16x8 a, s16x8 b, f32x16 c) {
  return __builtin_amdgcn_mfma_f32_32x32x16_bf16(a, b, c, 0, 0, 0);
}

DI f32x4 mfma16(s16x8 a, s16x8 b, f32x4 c) {
  return __builtin_amdgcn_mfma_f32_16x16x32_bf16(a, b, c, 0, 0, 0);
}

// ---------------- prep: weight transpose/convert + query cvt ----------------
// bid<2048: qbf[row=b*2048+n][c]=bf16(query[n][b][c]); else wconv (1088 tiles).
__global__ __launch_bounds__(256) void prep_kernel(
    const float* __restrict__ q, unsigned short* __restrict__ qbf,
    const float* __restrict__ Wq, const float* __restrict__ Wk,
    const float* __restrict__ Wv, const float* __restrict__ Wp,
    unsigned short* __restrict__ WqT, unsigned short* __restrict__ WkT,
    unsigned short* __restrict__ WvT, unsigned short* __restrict__ WpT)
{
  int bid = blockIdx.x;
  if (bid < 2048) {
    int gid = bid * 256 + threadIdx.x;    // 524288
    int row = gid >> 7;
    int c8 = (gid & 127) << 3;
    int b = row >> 11, n = row & 2047;
    size_t soff = ((size_t)n * 2 + b) * 1024 + c8;
    f32x4 v0 = *(const f32x4*)(q + soff);
    f32x4 v1 = *(const f32x4*)(q + soff + 4);
    union { unsigned u[4]; s16x8 v; } x;
    x.u[0] = cvtpk(v0.x, v0.y); x.u[1] = cvtpk(v0.z, v0.w);
    x.u[2] = cvtpk(v1.x, v1.y); x.u[3] = cvtpk(v1.z, v1.w);
    *(s16x8*)(qbf + (size_t)row * 1024 + c8) = x.v;
    return;
  }
  int wb = bid - 2048;
  const float* W; unsigned short* WT; int Ncols; int base;
  if (wb < 512)       { W = Wq; WT = WqT; Ncols = 1024; base = wb; }
  else if (wb < 1024) { W = Wp; WT = WpT; Ncols = 1024; base = wb - 512; }
  else if (wb < 1056) { W = Wk; WT = WkT; Ncols = 64;   base = wb - 1024; }
  else                { W = Wv; WT = WvT; Ncols = 64;   base = wb - 1056; }
  int nb = base >> 5, kb = base & 31;              // 64-n x 32-k tile
  int n = nb * 64 + (threadIdx.x & 63);
  int k = kb * 32 + (threadIdx.x >> 6) * 8;
  float f[8];
#pragma unroll
  for (int i = 0; i < 8; ++i) f[i] = W[(size_t)(k + i) * Ncols + n];
  union { unsigned u[4]; s16x8 v; } x;
#pragma unroll
  for (int i = 0; i < 4; ++i) x.u[i] = cvtpk(f[2 * i], f[2 * i + 1]);
  *(s16x8*)(WT + (size_t)n * 1024 + k) = x.v;
}

// ---------------- GEMM16 body (bf16 A via gll, prefetch dbuf): BM=128,BN=64 -
// MODE 0: qproj (out bf16 * scale).  MODE 2: out-proj (f32, (N,B,C) remap).
// As: 2 bufs x 8192 shorts; Bs: 2 bufs x 4096 shorts.
template<int MODE>
DI void gemm16_body(const unsigned short* __restrict__ A,
                    const unsigned short* __restrict__ Bt,
                    const float* __restrict__ bias, void* __restrict__ Cpv,
                    float scale, int bx, int by,
                    unsigned short* As, unsigned short* Bs)
{
  const int tid = threadIdx.x;
  const int lane = tid & 63, wave = tid >> 6;
  const int l16 = lane & 15, kq = lane >> 4;
  const int wr = wave >> 1, wc = wave & 1;   // WROWS=64, WCOLS=32; MI=4, NJ=2
  const int row0 = bx * 128;
  const int col0 = by * 64;

  f32x4 acc[4][2];
#pragma unroll
  for (int mi = 0; mi < 4; ++mi)
#pragma unroll
    for (int nj = 0; nj < 2; ++nj) acc[mi][nj] = f32x4{0.f, 0.f, 0.f, 0.f};

  auto STAGE = [&](int bf, int kt) {
    const int k0 = kt * 64;
    char* Ad = (char*)As + bf * 16384;
    char* Bd = (char*)Bs + bf * 8192;
#pragma unroll
    for (int i = 0; i < 4; ++i) {
      int o = i * 4096 + tid * 16;
      int r = o >> 7, c = (o & 127) >> 1;
      gll16(A + (size_t)(row0 + r) * 1024 + k0 + c, Ad + i * 4096 + wave * 1024);
    }
#pragma unroll
    for (int i = 0; i < 2; ++i) {
      int o = i * 4096 + tid * 16;
      int r = o >> 7, c = (o & 127) >> 1;
      gll16(Bt + (size_t)(col0 + r) * 1024 + k0 + c, Bd + i * 4096 + wave * 1024);
    }
  };

  STAGE(0, 0);
  __syncthreads();                 // implicit vmcnt(0) drain -> buf0 ready
  int cur = 0;
  for (int kt = 0; kt < 16; ++kt) {
    if (kt + 1 < 16) STAGE(cur ^ 1, kt + 1);   // prefetch next (hidden)
#pragma unroll
    for (int ks = 0; ks < 2; ++ks) {
      s16x8 af[4]; s16x8 bf2[2];
#pragma unroll
      for (int mi = 0; mi < 4; ++mi)
        af[mi] = *(const s16x8*)(As + cur * 8192 + (wr * 64 + mi * 16 + l16) * 64 + ks * 32 + kq * 8);
#pragma unroll
      for (int nj = 0; nj < 2; ++nj)
        bf2[nj] = *(const s16x8*)(Bs + cur * 4096 + (wc * 32 + nj * 16 + l16) * 64 + ks * 32 + kq * 8);
#pragma unroll
      for (int mi = 0; mi < 4; ++mi)
#pragma unroll
        for (int nj = 0; nj < 2; ++nj)
          acc[mi][nj] = mfma16(af[mi], bf2[nj], acc[mi][nj]);
    }
    __syncthreads();               // drains prefetch vmcnt + guards buf reuse
    cur ^= 1;
  }

  // epilogue; 16x16 C/D: col=lane&15, row=(lane>>4)*4 + r  [m89-verified]
#pragma unroll
  for (int mi = 0; mi < 4; ++mi)
#pragma unroll
  for (int nj = 0; nj < 2; ++nj) {
    int col = col0 + wc * 32 + nj * 16 + l16;
    int rowb = row0 + wr * 64 + mi * 16 + kq * 4;
    float bv = bias[col];
#pragma unroll
    for (int r = 0; r < 4; ++r) {
      int row = rowb + r;
      float val = acc[mi][nj][r] + bv;
      if constexpr (MODE == 0) {
        ((unsigned short*)Cpv)[(size_t)row * 1024 + col] = f2bf(val * scale);
      } else {
        ((float*)Cpv)[(size_t)(row & 2047) * 2048 + (size_t)(row >> 11) * 1024 + col] = val;
      }
    }
  }
}

// ---------------- kv-proj body: A = key/value f32 (reg-staged), FULL K ------
// Writes kproj / vprojT directly (+bias). As/Bs: 2 bufs x 4096 shorts each.
DI void gemmkv_body(const float* __restrict__ Akey, const float* __restrict__ Aval,
                    const unsigned short* __restrict__ Wk,
                    const unsigned short* __restrict__ Wv,
                    const float* __restrict__ bk, const float* __restrict__ bv,
                    unsigned short* __restrict__ kproj,
                    unsigned short* __restrict__ vprojT,
                    int bx, int sel,
                    unsigned short* As, unsigned short* Bs)
{
  const int tid = threadIdx.x;
  const int lane = tid & 63, wave = tid >> 6;
  const int l16 = lane & 15, kq = lane >> 4;
  const int wr = wave >> 1, wc = wave & 1;   // WROWS=32, WCOLS=32; MI=2, NJ=2
  const float* Af = sel ? Aval : Akey;
  const unsigned short* Bt = sel ? Wv : Wk;
  const int row0 = bx * 64;

  const int ar = tid >> 2, ac = (tid & 3) * 16;     // A: row 0..63, 16 f32/thread
  const int gm = row0 + ar;
  const size_t grow = sel ? (size_t)gm * 1024
                          : (size_t)((gm & 2047) * 2 + (gm >> 11)) * 1024;  // key remap

  auto LOADA = [&](int kt, f32x4* a4) {
#pragma unroll
    for (int i = 0; i < 4; ++i)
      a4[i] = *(const f32x4*)(Af + grow + kt * 64 + ac + i * 4);
  };
  auto WRITEA = [&](int bf, const f32x4* a4) {
    union { unsigned u[8]; s16x8 v[2]; } x;
#pragma unroll
    for (int i = 0; i < 4; ++i) {
      x.u[2 * i]     = cvtpk(a4[i].x, a4[i].y);
      x.u[2 * i + 1] = cvtpk(a4[i].z, a4[i].w);
    }
    *(s16x8*)(As + bf * 4096 + ar * 64 + ac)     = x.v[0];
    *(s16x8*)(As + bf * 4096 + ar * 64 + ac + 8) = x.v[1];
  };
  auto STAGEB = [&](int bf, int kt) {
#pragma unroll
    for (int i = 0; i < 2; ++i) {
      int o = i * 4096 + tid * 16;
      int r = o >> 7, c = (o & 127) >> 1;
      gll16(Bt + (size_t)r * 1024 + kt * 64 + c,
            (char*)Bs + bf * 8192 + i * 4096 + wave * 1024);
    }
  };

  f32x4 acc[2][2];
#pragma unroll
  for (int mi = 0; mi < 2; ++mi)
#pragma unroll
    for (int nj = 0; nj < 2; ++nj) acc[mi][nj] = f32x4{0.f, 0.f, 0.f, 0.f};

  f32x4 a4[4];
  LOADA(0, a4);
  STAGEB(0, 0);
  WRITEA(0, a4);
  __syncthreads();
  int cur = 0;
  for (int kt = 0; kt < 16; ++kt) {
    if (kt + 1 < 16) { LOADA(kt + 1, a4); STAGEB(cur ^ 1, kt + 1); }
#pragma unroll
    for (int ks = 0; ks < 2; ++ks) {
      s16x8 af[2]; s16x8 bf2[2];
#pragma unroll
      for (int mi = 0; mi < 2; ++mi)
        af[mi] = *(const s16x8*)(As + cur * 4096 + (wr * 32 + mi * 16 + l16) * 64 + ks * 32 + kq * 8);
#pragma unroll
      for (int nj = 0; nj < 2; ++nj)
        bf2[nj] = *(const s16x8*)(Bs + cur * 4096 + (wc * 32 + nj * 16 + l16) * 64 + ks * 32 + kq * 8);
#pragma unroll
      for (int mi = 0; mi < 2; ++mi)
#pragma unroll
        for (int nj = 0; nj < 2; ++nj)
          acc[mi][nj] = mfma16(af[mi], bf2[nj], acc[mi][nj]);
    }
    if (kt + 1 < 16) WRITEA(cur ^ 1, a4);   // vmcnt dep hidden under compute
    __syncthreads();
    cur ^= 1;
  }

  const float* bias = sel ? bv : bk;
#pragma unroll
  for (int mi = 0; mi < 2; ++mi)
#pragma unroll
  for (int nj = 0; nj < 2; ++nj) {
    int col = wc * 32 + nj * 16 + l16;
    int rowb = row0 + wr * 32 + mi * 16 + kq * 4;
    float bb = bias[col];
#pragma unroll
    for (int r = 0; r < 4; ++r) {
      int row = rowb + r;
      float val = acc[mi][nj][r] + bb;
      if (sel == 0)
        kproj[(size_t)row * 64 + col] = f2bf(val);
      else  // vprojT[b][d=col][n]
        vprojT[(size_t)(row >> 11) * 131072 + (size_t)col * 2048 + (row & 2047)] = f2bf(val);
    }
  }
}

// ---------------- merged qproj + kvproj launch (640 blocks, all co-resident) -
__global__ __launch_bounds__(256) void gemmqkv_kernel(
    const unsigned short* __restrict__ qbf, const unsigned short* __restrict__ WqT,
    const float* __restrict__ bq, unsigned short* __restrict__ qproj, float qscale,
    const float* __restrict__ key, const float* __restrict__ value,
    const unsigned short* __restrict__ WkT, const unsigned short* __restrict__ WvT,
    const float* __restrict__ bk, const float* __restrict__ bv,
    unsigned short* __restrict__ kproj, unsigned short* __restrict__ vprojT)
{
  __shared__ __align__(16) unsigned short SMEM[24576];   // 48KB union
  int bid = blockIdx.x;
  if (bid < 512) {
    gemm16_body<0>(qbf, WqT, bq, qproj, qscale, bid & 31, bid >> 5,
                   SMEM, SMEM + 16384);
  } else {
    int idx = bid - 512;                     // 0..127: 64 row-blocks x {k,v}
    gemmkv_body(key, value, WkT, WvT, bk, bv, kproj, vprojT,
                idx & 63, idx >> 6, SMEM, SMEM + 8192);
  }
}

// ---------------- out-proj launch ----------------
__global__ __launch_bounds__(256) void gemmout_kernel(
    const unsigned short* __restrict__ A, const unsigned short* __restrict__ Bt,
    const float* __restrict__ bias, float* __restrict__ Cpv)
{
  __shared__ __align__(16) unsigned short SMEM[24576];
  gemm16_body<2>(A, Bt, bias, (void*)Cpv, 1.0f, blockIdx.x, blockIdx.y,
                 SMEM, SMEM + 16384);
}

// ---------------- flash attention (MQA), swapped-operand 32x32 MFMA ---------
// Round 14: r13/r10 attn with ONE change: the P-pack cross-half exchange uses
// v_permlane32_swap_b32 (T12 primitive). swap(A,Cw) -> A'=[A_lo|Cw_lo],
// Cw'=[A_hi|Cw_hi] == exactly u[0]/u[2] of the old shfl+select pattern.
// Replaces 2 ds_bpermute + 4 v_cndmask per group; removes rA/rB temporaries
// (live state strictly decreases -> no r12-style spill risk). Bitwise-identical.
__global__ __launch_bounds__(512, 4) void attn_kernel(
    const unsigned short* __restrict__ qp, const unsigned short* __restrict__ kp,
    const unsigned short* __restrict__ vpt, unsigned short* __restrict__ xout)
{
  constexpr int KSTR = 72;                   // 64 + 8 pad (shorts)
  __shared__ unsigned short SM[36864];
#define KBUF(c, hh) (SM + ((c) * 2 + (hh)) * (64 * KSTR))
#define VBUF(c, hh) (SM + 18432 + ((c) * 2 + (hh)) * (64 * KSTR))

  const int tid = threadIdx.x;
  const int lane = tid & 63, wave = tid >> 6;  // 8 waves
  const int lq = lane & 31, hi = lane >> 5;
  const int qsub = wave & 3, half = wave >> 2;
  const int b = blockIdx.y >> 4, h = blockIdx.y & 15;
  const int q0 = blockIdx.x * 128 + qsub * 32;
  const size_t qrow = (size_t)(b * 2048 + q0 + lq);

  s16x8 qf[4];  // Q as B-operand: lane holds Q[q][d = s*16 + 8*hi .. +8)
#pragma unroll
  for (int s = 0; s < 4; ++s)
    qf[s] = *(const s16x8*)(qp + qrow * 1024 + h * 64 + s * 16 + hi * 8);

  f32x16 xacc0 = zero16(), xacc1 = zero16();
  float mrun = -1e30f, ssum = 0.f;

  const unsigned short* kb = kp + (size_t)b * (2048 * 64);
  const unsigned short* vb = vpt + (size_t)b * (64 * 2048);

  const int srow = tid >> 3;            // 0..63 (512 threads cover 64x64 tile)
  const int scol = (tid & 7) * 8;       // shorts; one 16B chunk per tile

  s16x8 kA, kB, vA, vB;
  {   // prologue: tiles 0 and 16 -> buf 0
    kA = *(const s16x8*)(kb + (size_t)srow * 64 + scol);
    kB = *(const s16x8*)(kb + (size_t)(16 * 64 + srow) * 64 + scol);
    vA = *(const s16x8*)(vb + (size_t)srow * 2048 + scol);
    vB = *(const s16x8*)(vb + (size_t)srow * 2048 + 16 * 64 + scol);
    *(s16x8*)(KBUF(0, 0) + srow * KSTR + scol) = kA;
    *(s16x8*)(KBUF(0, 1) + srow * KSTR + scol) = kB;
    *(s16x8*)(VBUF(0, 0) + srow * KSTR + scol) = vA;
    *(s16x8*)(VBUF(0, 1) + srow * KSTR + scol) = vB;
  }
  int cur = 0;

  for (int it = 0; it < 16; ++it) {
    __syncthreads();   // buf[cur] ready; buf[cur^1] free
    if (it + 1 < 16) { // issue next tile-pair loads (latency hidden under compute)
      kA = *(const s16x8*)(kb + (size_t)((it + 1) * 64 + srow) * 64 + scol);
      kB = *(const s16x8*)(kb + (size_t)((it + 17) * 64 + srow) * 64 + scol);
      vA = *(const s16x8*)(vb + (size_t)srow * 2048 + (it + 1) * 64 + scol);
      vB = *(const s16x8*)(vb + (size_t)srow * 2048 + (it + 17) * 64 + scol);
    }
    const unsigned short* Kc = KBUF(cur, half);
    const unsigned short* Vc = VBUF(cur, half);

    // S^T[kv][q], two 32-kv fragments
    f32x16 sacc0 = zero16(), sacc1 = zero16();
    __builtin_amdgcn_s_setprio(1);
#pragma unroll
    for (int s = 0; s < 4; ++s) {
      int c = s * 16 + hi * 8;
      s16x8 kf0 = *(const s16x8*)(Kc + lq * KSTR + c);
      s16x8 kf1 = *(const s16x8*)(Kc + (32 + lq) * KSTR + c);
      sacc0 = mfma32(kf0, qf[s], sacc0);
      sacc1 = mfma32(kf1, qf[s], sacc1);
    }
    __builtin_amdgcn_s_setprio(0);

    // online softmax, exp2 domain (scale folded into q-proj), defer-max THR=8
    float tm = fmaxf(max16_3(sacc0), max16_3(sacc1));
    tm = fmaxf(tm, __shfl_xor(tm, 32));
    if (!__all(tm <= mrun + 8.f)) {
      float mnew = fmaxf(mrun, tm);
      float alpha = __builtin_amdgcn_exp2f(mrun - mnew);
      ssum *= alpha;
#pragma unroll
      for (int e = 0; e < 16; ++e) { xacc0[e] *= alpha; xacc1[e] *= alpha; }
      mrun = mnew;
    }
    f32x16 p0, p1;
#pragma unroll
    for (int e = 0; e < 16; ++e) p0[e] = __builtin_amdgcn_exp2f(sacc0[e] - mrun);
#pragma unroll
    for (int e = 0; e < 16; ++e) p1[e] = __builtin_amdgcn_exp2f(sacc1[e] - mrun);
    float tsum = sum16(p0) + sum16(p1);
    tsum += __shfl_xor(tsum, 32);
    ssum += tsum;

    // In-register P^T pack via permlane32_swap. Lane holds p[e] at
    // kv=(e&3)+8*(e>>2)+4*hi (+32 for p1). After swap(A,Cw):
    // A'=[A_lo|Cw_lo]=u[0], Cw'=[A_hi|Cw_hi]=u[2]; same for (Bw,Dw)->u[1],u[3].
    s16x8 pb[4];
#pragma unroll
    for (int grp = 0; grp < 4; ++grp) {       // grp: {p0,p1} x {e0-7, e8-15}
      const f32x16& pp = (grp < 2) ? p0 : p1;
      const int eb = (grp & 1) * 8;
      unsigned A  = cvtpk(pp[eb + 0], pp[eb + 1]);
      unsigned Bw = cvtpk(pp[eb + 2], pp[eb + 3]);
      unsigned Cw = cvtpk(pp[eb + 4], pp[eb + 5]);
      unsigned Dw = cvtpk(pp[eb + 6], pp[eb + 7]);
      asm("v_permlane32_swap_b32 %0, %1" : "+v"(A), "+v"(Cw));
      asm("v_permlane32_swap_b32 %0, %1" : "+v"(Bw), "+v"(Dw));
      union { unsigned u[4]; s16x8 v; } pk_;
      pk_.u[0] = A;
      pk_.u[1] = Bw;
      pk_.u[2] = Cw;
      pk_.u[3] = Dw;
      pb[grp] = pk_.v;
    }

    // X^T += V^T @ P^T  (two 32-d fragments)
    __builtin_amdgcn_s_setprio(1);
#pragma unroll
    for (int kvs = 0; kvs < 4; ++kvs) {
      int c = kvs * 16 + hi * 8;
      s16x8 vf0 = *(const s16x8*)(Vc + lq * KSTR + c);
      s16x8 vf1 = *(const s16x8*)(Vc + (32 + lq) * KSTR + c);
      xacc0 = mfma32(vf0, pb[kvs], xacc0);
      xacc1 = mfma32(vf1, pb[kvs], xacc1);
    }
    __builtin_amdgcn_s_setprio(0);

    if (it + 1 < 16) {  // write staged regs -> other buffer
      *(s16x8*)(KBUF(cur ^ 1, 0) + srow * KSTR + scol) = kA;
      *(s16x8*)(KBUF(cur ^ 1, 1) + srow * KSTR + scol) = kB;
      *(s16x8*)(VBUF(cur ^ 1, 0) + srow * KSTR + scol) = vA;
      *(s16x8*)(VBUF(cur ^ 1, 1) + srow * KSTR + scol) = vB;
      cur ^= 1;
    }
  }

  // ---- merge the two kv-halves (pair: waves qsub & qsub+4), via LDS ----
  __syncthreads();                     // all K/V reads done; SM reusable
  float* msc = (float*)SM;             // stride 37 f32 per lane
  const int mi_ = (qsub * 64 + lane) * 37;
  if (half == 1) {
#pragma unroll
    for (int e = 0; e < 16; ++e) { msc[mi_ + e] = xacc0[e]; msc[mi_ + 16 + e] = xacc1[e]; }
    msc[mi_ + 32] = mrun;
    msc[mi_ + 33] = ssum;
  }
  __syncthreads();
  if (half == 0) {
    float pm = msc[mi_ + 32], ps = msc[mi_ + 33];
    float mf = fmaxf(mrun, pm);
    float aa = __builtin_amdgcn_exp2f(mrun - mf);
    float bb = __builtin_amdgcn_exp2f(pm - mf);
    float inv = 1.0f / (ssum * aa + ps * bb);
#pragma unroll
    for (int dj = 0; dj < 2; ++dj) {
      const f32x16 xa = dj ? xacc1 : xacc0;
#pragma unroll
      for (int g = 0; g < 4; ++g) {
        u16x4 o4;
#pragma unroll
        for (int r = 0; r < 4; ++r) {
          int e = g * 4 + r;
          float merged = xa[e] * aa + msc[mi_ + dj * 16 + e] * bb;
          o4[r] = f2bf(merged * inv);
        }
        int d0 = dj * 32 + 8 * g + 4 * hi;
        *(u16x4*)(xout + qrow * 1024 + h * 64 + d0) = o4;
      }
    }
  }
#undef KBUF
#undef VBUF
}

// -----------------------------------------------------------------------------
extern "C" void kernel_launch(void* const* d_in, const int* in_sizes, int n_in,
                              void* d_out, int out_size, void* d_ws, size_t ws_size,
                              hipStream_t stream)
{
  const float* query = (const float*)d_in[0];
  const float* key   = (const float*)d_in[1];
  const float* value = (const float*)d_in[2];
  const float* Wq = (const float*)d_in[4];
  const float* bq = (const float*)d_in[5];
  const float* Wk = (const float*)d_in[6];
  const float* bk = (const float*)d_in[7];
  const float* Wv = (const float*)d_in[8];
  const float* bv = (const float*)d_in[9];
  const float* Wp = (const float*)d_in[10];
  const float* bp = (const float*)d_in[11];

  char* ws = (char*)d_ws;
  unsigned short* WqT    = (unsigned short*)(ws);
  unsigned short* WpT    = (unsigned short*)(ws + (2u << 20));
  unsigned short* WkT    = (unsigned short*)(ws + (4u << 20));
  unsigned short* WvT    = (unsigned short*)(ws + (4u << 20) + (128u << 10));
  unsigned short* kproj  = (unsigned short*)(ws + (5u << 20));
  unsigned short* vprojT = (unsigned short*)(ws + (5u << 20) + (512u << 10));
  unsigned short* qproj  = (unsigned short*)(ws + (6u << 20));     // 8.39MB
  unsigned short* xbuf   = (unsigned short*)(ws + (15u << 20));    // 8.39MB
  unsigned short* qbf    = (unsigned short*)d_out;                  // dead until out-proj

  prep_kernel<<<dim3(3136), 256, 0, stream>>>(
      query, qbf, Wq, Wk, Wv, Wp, WqT, WkT, WvT, WpT);

  const float qscale = 0.18033688011112042f;  // hd^-0.5 * log2(e)
  gemmqkv_kernel<<<dim3(640), 256, 0, stream>>>(
      qbf, WqT, bq, qproj, qscale, key, value, WkT, WvT, bk, bv, kproj, vprojT);
  attn_kernel<<<dim3(16, 32), 512, 0, stream>>>(qproj, kproj, vprojT, xbuf);
  gemmout_kernel<<<dim3(32, 16), 256, 0, stream>>>(xbuf, WpT, bp, (float*)d_out);
}